// Round 16
// baseline (240.301 us; speedup 1.0000x reference)
//
#include <hip/hip_runtime.h>
#include <hip/hip_bf16.h>

typedef __attribute__((ext_vector_type(8))) short bf16x8;
typedef __attribute__((ext_vector_type(4))) float f32x4;
typedef __attribute__((ext_vector_type(16))) float f32x16;
typedef __attribute__((ext_vector_type(4))) unsigned int u32x4;

__device__ inline unsigned short f2bf(float f) {
    unsigned int u = __builtin_bit_cast(unsigned int, f);
    u += 0x7FFFu + ((u >> 16) & 1u);
    return (unsigned short)(u >> 16);
}
__device__ inline float bf2f(unsigned short h) {
    unsigned int u = ((unsigned int)h) << 16;
    return __builtin_bit_cast(float, u);
}
// hardware packed f32->bf16 (RNE), gfx950: no builtin -> inline asm
__device__ inline unsigned int cvtpk(float lo, float hi) {
    unsigned int r;
    asm("v_cvt_pk_bf16_f32 %0, %1, %2" : "=v"(r) : "v"(lo), "v"(hi));
    return r;
}

// ---------------- conversion kernels ----------------

__global__ void k_conv_x(const float* __restrict__ in, unsigned short* __restrict__ out, int n4) {
    int i = blockIdx.x * blockDim.x + threadIdx.x;
    if (i >= n4) return;
    float4 v = ((const float4*)in)[i];
    uint2 o;
    o.x = (unsigned)f2bf(v.x) | ((unsigned)f2bf(v.y) << 16);
    o.y = (unsigned)f2bf(v.z) | ((unsigned)f2bf(v.w) << 16);
    ((uint2*)out)[i] = o;
}

// W fp32 [2048][2048] -> W^T bf16 [2048][2048]; z selects weight
__global__ void k_wT(const float* __restrict__ w0, const float* __restrict__ w1,
                     const float* __restrict__ w2, const float* __restrict__ w3,
                     unsigned short* __restrict__ out) {
    __shared__ float tile[32][33];
    int z = blockIdx.z;
    const float* W = (z == 0) ? w0 : (z == 1) ? w1 : (z == 2) ? w2 : w3;
    unsigned short* O = out + (size_t)z * 2048 * 2048;
    int n0 = blockIdx.x * 32, k0 = blockIdx.y * 32;
    int tx = threadIdx.x & 31, ty = threadIdx.x >> 5;
#pragma unroll
    for (int j = 0; j < 4; ++j)
        tile[ty + j * 8][tx] = W[(size_t)(k0 + ty + j * 8) * 2048 + n0 + tx];
    __syncthreads();
#pragma unroll
    for (int j = 0; j < 4; ++j)
        O[(size_t)(n0 + ty + j * 8) * 2048 + k0 + tx] = f2bf(tile[tx][ty + j * 8]);
}

// ---------------- GEMM: C[M][N] = A[M][K] * Bt[N][K]^T ----------------
// R3 hot loop (128x128 tile, 4 waves, 2-barrier, gload_lds w16, granule-XOR).
// Wave N-columns remapped to wn*32 + (ni&1)*16 + (ni>>1)*64 so each lane holds
// RoPE pairs (d, d+64) in (ni, ni+2).
// Config A (empirical best, 240.4us total): scattered fused epilogues.
// R12/R14 showed LDS-staged epilogues improve gemm0 per-dispatch (112.5 vs
// 119.4) but regress TOTAL by 16-22us (unidentified downstream interaction) --
// reverted to A.
template <int OUT_MODE>
__global__ __launch_bounds__(256, 6) void gemm_bt(const unsigned short* __restrict__ A,
                                                  const unsigned short* __restrict__ Bt,
                                                  void* __restrict__ outp,
                                                  unsigned short* __restrict__ vtp,
                                                  int M, int N, int K) {
    __shared__ __align__(16) unsigned short As[128 * 64];
    __shared__ __align__(16) unsigned short Bs[128 * 64];
    const int tid = threadIdx.x, w = tid >> 6, l = tid & 63;
    const int m0 = blockIdx.y * 128, n0 = blockIdx.x * 128;
    const int wm = w >> 1, wn = w & 1;
    const int l15 = l & 15, lq = l >> 4;
    f32x4 acc[4][4] = {};
    const int lr = l >> 3, lg = l & 7;
    const int srcg = lg ^ lr;  // source granule (row&7 == lr since r0 % 8 == 0)

    const int nkt = K >> 6;
    for (int kt = 0; kt < nkt; ++kt) {
        if (kt) __syncthreads();
#pragma unroll
        for (int i = 0; i < 4; ++i) {
            int r0 = (w * 4 + i) * 8;
            int row = r0 + lr;
            const unsigned short* sa = A + (size_t)(m0 + row) * K + kt * 64 + srcg * 8;
            __builtin_amdgcn_global_load_lds((const void*)sa, (void*)&As[(w * 4 + i) * 512], 16, 0, 0);
            const unsigned short* sb = Bt + (size_t)(n0 + row) * K + kt * 64 + srcg * 8;
            __builtin_amdgcn_global_load_lds((const void*)sb, (void*)&Bs[(w * 4 + i) * 512], 16, 0, 0);
        }
        __syncthreads();
#pragma unroll
        for (int kb = 0; kb < 2; ++kb) {
            bf16x8 af[4], bfr[4];
#pragma unroll
            for (int mi = 0; mi < 4; ++mi) {
                int row = wm * 64 + mi * 16 + l15;
                int g = (kb * 4 + lq) ^ (row & 7);
                af[mi] = *(const bf16x8*)&As[row * 64 + g * 8];
            }
#pragma unroll
            for (int ni = 0; ni < 4; ++ni) {
                int row = wn * 32 + (ni & 1) * 16 + (ni >> 1) * 64 + l15;  // colmap
                int g = (kb * 4 + lq) ^ (row & 7);
                bfr[ni] = *(const bf16x8*)&Bs[row * 64 + g * 8];
            }
#pragma unroll
            for (int mi = 0; mi < 4; ++mi)
#pragma unroll
                for (int ni = 0; ni < 4; ++ni)
                    acc[mi][ni] = __builtin_amdgcn_mfma_f32_16x16x32_bf16(af[mi], bfr[ni],
                                                                          acc[mi][ni], 0, 0, 0);
        }
    }
    __builtin_amdgcn_sched_barrier(0);  // keep epilogue out of the K-loop

    if constexpr (OUT_MODE == 0) {
        const int tsel = n0 >> 11, nloc = n0 & 2047;
        if (tsel < 2) {
            // Q/K: RoPE in-register, trig on the fly (no memory traffic).
            unsigned short* op = (unsigned short*)outp + (size_t)tsel * M * 2048;
            const float scale = (tsel == 0) ? 0.12751742f : 1.0f;  // log2e/sqrt(128)
#pragma unroll
            for (int ni = 0; ni < 2; ++ni) {
                const int i = wn * 32 + ni * 16 + l15;  // d in [0,64)
                // rev_freq = 10000^(-i/64) / (2*pi)
                const float rf =
                    __builtin_amdgcn_exp2f(-(float)i * 0.20762051f - 2.6514961f);
#pragma unroll
                for (int mi = 0; mi < 4; ++mi)
#pragma unroll
                    for (int r = 0; r < 4; ++r) {
                        int row = m0 + wm * 64 + mi * 16 + lq * 4 + r;
                        int sp = row & 2047;
                        float rev = __builtin_amdgcn_fractf((float)sp * rf);
                        float cs = __builtin_amdgcn_cosf(rev);   // cos(2*pi*rev)
                        float sn = __builtin_amdgcn_sinf(rev);   // sin(2*pi*rev)
                        float a = acc[mi][ni][r], bb = acc[mi][ni + 2][r];
                        op[(size_t)row * 2048 + nloc + i]      = f2bf((a * cs - bb * sn) * scale);
                        op[(size_t)row * 2048 + nloc + i + 64] = f2bf((bb * cs + a * sn) * scale);
                    }
            }
        } else {
            // V: fused transpose -> vT[(b*16+h)*128 + d][s], packed 8B along s
            const int h = nloc >> 7;
            const int bsel = m0 >> 11;
            const int sp0 = (m0 & 2047) + wm * 64;
#pragma unroll
            for (int mi = 0; mi < 4; ++mi)
#pragma unroll
                for (int ni = 0; ni < 4; ++ni) {
                    int d = wn * 32 + (ni & 1) * 16 + (ni >> 1) * 64 + l15;
                    uint2 pv;
                    pv.x = cvtpk(acc[mi][ni][0], acc[mi][ni][1]);
                    pv.y = cvtpk(acc[mi][ni][2], acc[mi][ni][3]);
                    *(uint2*)&vtp[((size_t)((bsel * 16 + h) * 128 + d)) * 2048 + sp0 + mi * 16 + lq * 4] = pv;
                }
        }
    } else {
        float* op = (float*)outp;
#pragma unroll
        for (int mi = 0; mi < 4; ++mi)
#pragma unroll
            for (int ni = 0; ni < 4; ++ni)
#pragma unroll
                for (int r = 0; r < 4; ++r) {
                    int row = m0 + wm * 64 + mi * 16 + lq * 4 + r;
                    int col = n0 + wn * 32 + (ni & 1) * 16 + (ni >> 1) * 64 + l15;
                    op[(size_t)row * 2048 + col] = acc[mi][ni][r];
                }
    }
}

// ---------------- flash attention (causal), v4: 1 tile/block, 512 blocks ----
// One 128-row q-tile per block, grid 512 = 2 blocks/CU; LPT order (biggest
// tiles first). Softmax in-lane (swapped 32x32 MFMA); P repack via hw cvt_pk +
// 2x shfl_xor(32); dbuf K/V staging with counted vmcnt(8).
__global__ __launch_bounds__(256, 2) void k_attn(const unsigned short* __restrict__ Qp,
                                                 const unsigned short* __restrict__ Kp,
                                                 const unsigned short* __restrict__ VTp,
                                                 unsigned short* __restrict__ ctx) {
    __shared__ __align__(16) unsigned short Ks[2][64 * 128];  // [kpos][d], granule-XOR swz
    __shared__ __align__(16) unsigned short Vs[2][128 * 64];  // [d][kpos], granule-XOR swz
    const int tid = threadIdx.x, w = tid >> 6, l = tid & 63;
    const int l31 = l & 31, hi = l >> 5;
    const int x = blockIdx.x, bh = x & 31;
    const int t = 15 - (x >> 5);         // LPT: biggest tiles first
    const int b = bh >> 4, h = bh & 15;
    const size_t b2048 = (size_t)b * 2048;
    const int h128 = h * 128;
    const size_t bh128 = (size_t)bh * 128;

    auto stage = [&](int kv) {
        const int bsel = kv & 1;
        const size_t kvoff = (size_t)kv * 64;
#pragma unroll
        for (int i = 0; i < 4; ++i) {
            int gi = w * 256 + i * 64 + l;          // K: 64 rows x 16 granules
            int row = gi >> 4, g = gi & 15;
            int sg = g ^ (row & 7);
            const unsigned short* src = Kp + (b2048 + kvoff + row) * 2048 + h128 + sg * 8;
            __builtin_amdgcn_global_load_lds((const void*)src,
                                             (void*)&Ks[bsel][w * 2048 + i * 512], 16, 0, 0);
        }
#pragma unroll
        for (int i = 0; i < 4; ++i) {
            int gi = w * 256 + i * 64 + l;          // V: 128 rows x 8 granules
            int row = gi >> 3, g = gi & 7;
            int sg = g ^ (row & 7);
            const unsigned short* src = VTp + (bh128 + row) * 2048 + kvoff + sg * 8;
            __builtin_amdgcn_global_load_lds((const void*)src,
                                             (void*)&Vs[bsel][w * 2048 + i * 512], 16, 0, 0);
        }
    };

    const int q0 = t * 128;
    const int wrow0 = q0 + w * 32;
    const int qg = wrow0 + l31;          // this lane's q row

    // Q in registers: B-frag layout, q = l31, d = ds*16 + hi*8 + j
    bf16x8 qf[8];
    {
        const unsigned short* qb = Qp + (b2048 + qg) * 2048 + h128 + hi * 8;
#pragma unroll
        for (int ds = 0; ds < 8; ++ds) qf[ds] = *(const bf16x8*)(qb + ds * 16);
#pragma unroll
        for (int ds = 0; ds < 8; ++ds) asm volatile("" ::"v"(qf[ds]));
    }
    f32x16 Oa[4] = {};
    float m2 = -1e30f, l2 = 0.f;
    const int kvmax = 2 * t + 1;

    stage(0);
    for (int kv = 0; kv <= kvmax; ++kv) {
        const int cur = kv & 1;
        if (kv < kvmax) {
            stage(kv + 1);
            asm volatile("s_waitcnt vmcnt(8)" ::: "memory");
        } else {
            asm volatile("s_waitcnt vmcnt(0)" ::: "memory");
        }
        __builtin_amdgcn_s_barrier();
        __builtin_amdgcn_sched_barrier(0);

        const int kvb = kv * 64;
        if (kvb <= wrow0 + 31) {  // wave has unmasked rows
            // S[kpos][q] = K·Q^T : A = K rows, B = Q
            f32x16 S[2] = {};
            __builtin_amdgcn_s_setprio(1);
#pragma unroll
            for (int ds = 0; ds < 8; ++ds)
#pragma unroll
                for (int st = 0; st < 2; ++st) {
                    int row = st * 32 + l31;
                    int g = (ds * 2 + hi) ^ (row & 7);
                    bf16x8 kf = *(const bf16x8*)&Ks[cur][row * 128 + g * 8];
                    S[st] = __builtin_amdgcn_mfma_f32_32x32x16_bf16(kf, qf[ds], S[st], 0, 0, 0);
                }
            __builtin_amdgcn_s_setprio(0);

            if (kvb + 63 > wrow0) {  // diagonal: elementwise causal mask
#pragma unroll
                for (int st = 0; st < 2; ++st)
#pragma unroll
                    for (int r = 0; r < 16; ++r) {
                        int kpos = kvb + st * 32 + (r & 3) + 8 * (r >> 2) + 4 * hi;
                        if (kpos > qg) S[st][r] = -1e30f;
                    }
            }

            // in-lane softmax (lane owns one P-row; l^32 partner shares q)
            float pmax = -1e30f;
#pragma unroll
            for (int st = 0; st < 2; ++st)
#pragma unroll
                for (int r = 0; r < 16; ++r) pmax = fmaxf(pmax, S[st][r]);
            pmax = fmaxf(pmax, __shfl_xor(pmax, 32));
            if (__any(pmax > m2 + 8.0f)) {  // defer-max (T13)
                float mn = fmaxf(m2, pmax);
                float sc = __builtin_amdgcn_exp2f(m2 - mn);
                m2 = mn;
                l2 *= sc;
#pragma unroll
                for (int dt = 0; dt < 4; ++dt)
#pragma unroll
                    for (int e = 0; e < 16; ++e) Oa[dt][e] *= sc;
            }
            float rs = 0.f;
#pragma unroll
            for (int st = 0; st < 2; ++st)
#pragma unroll
                for (int r = 0; r < 16; ++r) {
                    float p = __builtin_amdgcn_exp2f(S[st][r] - m2);
                    S[st][r] = p;
                    rs += p;
                }
            rs += __shfl_xor(rs, 32);
            l2 += rs;

            // repack P -> B-frags via hw cvt_pk (k = hi*8+j per 16-kpos step)
            bf16x8 pfrag[4];
#pragma unroll
            for (int ks = 0; ks < 4; ++ks) {
                const int st = ks >> 1, base = (ks & 1) * 8;
                unsigned int x0 = cvtpk(S[st][base + 0], S[st][base + 1]);
                unsigned int x1 = cvtpk(S[st][base + 2], S[st][base + 3]);
                unsigned int y0 = cvtpk(S[st][base + 4], S[st][base + 5]);
                unsigned int y1 = cvtpk(S[st][base + 6], S[st][base + 7]);
                unsigned int t0 = hi ? x0 : y0, t1 = hi ? x1 : y1;
                t0 = (unsigned int)__shfl_xor((int)t0, 32);
                t1 = (unsigned int)__shfl_xor((int)t1, 32);
                u32x4 fw;
                fw.x = hi ? t0 : x0;
                fw.y = hi ? t1 : x1;
                fw.z = hi ? y0 : t0;
                fw.w = hi ? y1 : t1;
                pfrag[ks] = __builtin_bit_cast(bf16x8, fw);
            }

            // O[d][q] += Vt·P : A = Vt rows, B = P
            __builtin_amdgcn_s_setprio(1);
#pragma unroll
            for (int ks = 0; ks < 4; ++ks)
#pragma unroll
                for (int dt = 0; dt < 4; ++dt) {
                    int row = dt * 32 + l31;
                    int g = (ks * 2 + hi) ^ (row & 7);
                    bf16x8 vf = *(const bf16x8*)&Vs[cur][row * 64 + g * 8];
                    Oa[dt] = __builtin_amdgcn_mfma_f32_32x32x16_bf16(vf, pfrag[ks], Oa[dt], 0, 0, 0);
                }
            __builtin_amdgcn_s_setprio(0);
        }
        __builtin_amdgcn_sched_barrier(0);
        __builtin_amdgcn_s_barrier();
    }

    // epilogue: d = dt*32 + (r&3) + 8*(r>>2) + 4*hi -> 8B packed stores
    float inv = 1.0f / l2;
    unsigned short* cb = ctx + (b2048 + qg) * 2048 + h128;
#pragma unroll
    for (int dt = 0; dt < 4; ++dt)
#pragma unroll
        for (int g = 0; g < 4; ++g) {
            uint2 pv;
            pv.x = cvtpk(Oa[dt][4 * g + 0] * inv, Oa[dt][4 * g + 1] * inv);
            pv.y = cvtpk(Oa[dt][4 * g + 2] * inv, Oa[dt][4 * g + 3] * inv);
            *(uint2*)(cb + dt * 32 + 8 * g + 4 * hi) = pv;
        }
}

// ---------------- launch ----------------

extern "C" void kernel_launch(void* const* d_in, const int* in_sizes, int n_in,
                              void* d_out, int out_size, void* d_ws, size_t ws_size,
                              hipStream_t stream) {
    const float* x  = (const float*)d_in[0];
    const float* wq = (const float*)d_in[1];
    const float* wk = (const float*)d_in[2];
    const float* wv = (const float*)d_in[3];
    const float* wo = (const float*)d_in[4];

    char* ws = (char*)d_ws;
    unsigned short* xb  = (unsigned short*)(ws);                 // 16,777,216 B (reused as ctx)
    unsigned short* wT  = (unsigned short*)(ws + 16777216);      // 33,554,432 B [4][2048][2048]
    unsigned short* qkv = (unsigned short*)(ws + 50331648);      // 50,331,648 B [3][4096][2048] (V third unused)
    unsigned short* vT  = (unsigned short*)(ws + 100663296);     // 16,777,216 B [2][16][128][2048]
    unsigned short* ctx = xb;                                    // xb dead after gemm0

    k_conv_x<<<8192, 256, 0, stream>>>(x, xb, 2097152);
    k_wT<<<dim3(64, 64, 4), 256, 0, stream>>>(wq, wk, wv, wo, wT);
    gemm_bt<0><<<dim3(48, 32), 256, 0, stream>>>(xb, wT, (void*)qkv, vT, 4096, 6144, 2048);
    k_attn<<<512, 256, 0, stream>>>(qkv, qkv + 8388608, vT, ctx);
    gemm_bt<1><<<dim3(16, 32), 256, 0, stream>>>(ctx, wT + (size_t)3 * 4194304, d_out, vT,
                                                 4096, 2048, 2048);
}

// Round 17
// 240.240 us; speedup vs baseline: 1.0003x; 1.0003x over previous
//
#include <hip/hip_runtime.h>
#include <hip/hip_bf16.h>

typedef __attribute__((ext_vector_type(8))) short bf16x8;
typedef __attribute__((ext_vector_type(4))) float f32x4;
typedef __attribute__((ext_vector_type(16))) float f32x16;
typedef __attribute__((ext_vector_type(4))) unsigned int u32x4;

__device__ inline unsigned short f2bf(float f) {
    unsigned int u = __builtin_bit_cast(unsigned int, f);
    u += 0x7FFFu + ((u >> 16) & 1u);
    return (unsigned short)(u >> 16);
}
__device__ inline float bf2f(unsigned short h) {
    unsigned int u = ((unsigned int)h) << 16;
    return __builtin_bit_cast(float, u);
}
// hardware packed f32->bf16 (RNE), gfx950: no builtin -> inline asm
__device__ inline unsigned int cvtpk(float lo, float hi) {
    unsigned int r;
    asm("v_cvt_pk_bf16_f32 %0, %1, %2" : "=v"(r) : "v"(lo), "v"(hi));
    return r;
}

// ---------------- conversion kernels ----------------

__global__ void k_conv_x(const float* __restrict__ in, unsigned short* __restrict__ out, int n4) {
    int i = blockIdx.x * blockDim.x + threadIdx.x;
    if (i >= n4) return;
    float4 v = ((const float4*)in)[i];
    uint2 o;
    o.x = (unsigned)f2bf(v.x) | ((unsigned)f2bf(v.y) << 16);
    o.y = (unsigned)f2bf(v.z) | ((unsigned)f2bf(v.w) << 16);
    ((uint2*)out)[i] = o;
}

// W fp32 [2048][2048] -> W^T bf16 [2048][2048]; z selects weight
__global__ void k_wT(const float* __restrict__ w0, const float* __restrict__ w1,
                     const float* __restrict__ w2, const float* __restrict__ w3,
                     unsigned short* __restrict__ out) {
    __shared__ float tile[32][33];
    int z = blockIdx.z;
    const float* W = (z == 0) ? w0 : (z == 1) ? w1 : (z == 2) ? w2 : w3;
    unsigned short* O = out + (size_t)z * 2048 * 2048;
    int n0 = blockIdx.x * 32, k0 = blockIdx.y * 32;
    int tx = threadIdx.x & 31, ty = threadIdx.x >> 5;
#pragma unroll
    for (int j = 0; j < 4; ++j)
        tile[ty + j * 8][tx] = W[(size_t)(k0 + ty + j * 8) * 2048 + n0 + tx];
    __syncthreads();
#pragma unroll
    for (int j = 0; j < 4; ++j)
        O[(size_t)(n0 + ty + j * 8) * 2048 + k0 + tx] = f2bf(tile[tx][ty + j * 8]);
}

// ---------------- GEMM: C[M][N] = A[M][K] * Bt[N][K]^T ----------------
// R3 hot loop (128x128 tile, 4 waves, 2-barrier, gload_lds w16, granule-XOR).
// Wave N-columns remapped to wn*32 + (ni&1)*16 + (ni>>1)*64 so each lane holds
// RoPE pairs (d, d+64) in (ni, ni+2).
// Config A (empirical best): scattered fused epilogues, on-the-fly trig.
template <int OUT_MODE>
__global__ __launch_bounds__(256, 6) void gemm_bt(const unsigned short* __restrict__ A,
                                                  const unsigned short* __restrict__ Bt,
                                                  void* __restrict__ outp,
                                                  unsigned short* __restrict__ vtp,
                                                  int M, int N, int K) {
    __shared__ __align__(16) unsigned short As[128 * 64];
    __shared__ __align__(16) unsigned short Bs[128 * 64];
    const int tid = threadIdx.x, w = tid >> 6, l = tid & 63;
    const int m0 = blockIdx.y * 128, n0 = blockIdx.x * 128;
    const int wm = w >> 1, wn = w & 1;
    const int l15 = l & 15, lq = l >> 4;
    f32x4 acc[4][4] = {};
    const int lr = l >> 3, lg = l & 7;
    const int srcg = lg ^ lr;  // source granule (row&7 == lr since r0 % 8 == 0)

    const int nkt = K >> 6;
    for (int kt = 0; kt < nkt; ++kt) {
        if (kt) __syncthreads();
#pragma unroll
        for (int i = 0; i < 4; ++i) {
            int r0 = (w * 4 + i) * 8;
            int row = r0 + lr;
            const unsigned short* sa = A + (size_t)(m0 + row) * K + kt * 64 + srcg * 8;
            __builtin_amdgcn_global_load_lds((const void*)sa, (void*)&As[(w * 4 + i) * 512], 16, 0, 0);
            const unsigned short* sb = Bt + (size_t)(n0 + row) * K + kt * 64 + srcg * 8;
            __builtin_amdgcn_global_load_lds((const void*)sb, (void*)&Bs[(w * 4 + i) * 512], 16, 0, 0);
        }
        __syncthreads();
#pragma unroll
        for (int kb = 0; kb < 2; ++kb) {
            bf16x8 af[4], bfr[4];
#pragma unroll
            for (int mi = 0; mi < 4; ++mi) {
                int row = wm * 64 + mi * 16 + l15;
                int g = (kb * 4 + lq) ^ (row & 7);
                af[mi] = *(const bf16x8*)&As[row * 64 + g * 8];
            }
#pragma unroll
            for (int ni = 0; ni < 4; ++ni) {
                int row = wn * 32 + (ni & 1) * 16 + (ni >> 1) * 64 + l15;  // colmap
                int g = (kb * 4 + lq) ^ (row & 7);
                bfr[ni] = *(const bf16x8*)&Bs[row * 64 + g * 8];
            }
#pragma unroll
            for (int mi = 0; mi < 4; ++mi)
#pragma unroll
                for (int ni = 0; ni < 4; ++ni)
                    acc[mi][ni] = __builtin_amdgcn_mfma_f32_16x16x32_bf16(af[mi], bfr[ni],
                                                                          acc[mi][ni], 0, 0, 0);
        }
    }
    __builtin_amdgcn_sched_barrier(0);  // keep epilogue out of the K-loop

    if constexpr (OUT_MODE == 0) {
        const int tsel = n0 >> 11, nloc = n0 & 2047;
        if (tsel < 2) {
            // Q/K: RoPE in-register, trig on the fly (no memory traffic).
            unsigned short* op = (unsigned short*)outp + (size_t)tsel * M * 2048;
            const float scale = (tsel == 0) ? 0.12751742f : 1.0f;  // log2e/sqrt(128)
#pragma unroll
            for (int ni = 0; ni < 2; ++ni) {
                const int i = wn * 32 + ni * 16 + l15;  // d in [0,64)
                // rev_freq = 10000^(-i/64) / (2*pi)
                const float rf =
                    __builtin_amdgcn_exp2f(-(float)i * 0.20762051f - 2.6514961f);
#pragma unroll
                for (int mi = 0; mi < 4; ++mi)
#pragma unroll
                    for (int r = 0; r < 4; ++r) {
                        int row = m0 + wm * 64 + mi * 16 + lq * 4 + r;
                        int sp = row & 2047;
                        float rev = __builtin_amdgcn_fractf((float)sp * rf);
                        float cs = __builtin_amdgcn_cosf(rev);   // cos(2*pi*rev)
                        float sn = __builtin_amdgcn_sinf(rev);   // sin(2*pi*rev)
                        float a = acc[mi][ni][r], bb = acc[mi][ni + 2][r];
                        op[(size_t)row * 2048 + nloc + i]      = f2bf((a * cs - bb * sn) * scale);
                        op[(size_t)row * 2048 + nloc + i + 64] = f2bf((bb * cs + a * sn) * scale);
                    }
            }
        } else {
            // V: fused transpose -> vT[(b*16+h)*128 + d][s], packed 8B along s
            const int h = nloc >> 7;
            const int bsel = m0 >> 11;
            const int sp0 = (m0 & 2047) + wm * 64;
#pragma unroll
            for (int mi = 0; mi < 4; ++mi)
#pragma unroll
                for (int ni = 0; ni < 4; ++ni) {
                    int d = wn * 32 + (ni & 1) * 16 + (ni >> 1) * 64 + l15;
                    uint2 pv;
                    pv.x = cvtpk(acc[mi][ni][0], acc[mi][ni][1]);
                    pv.y = cvtpk(acc[mi][ni][2], acc[mi][ni][3]);
                    *(uint2*)&vtp[((size_t)((bsel * 16 + h) * 128 + d)) * 2048 + sp0 + mi * 16 + lq * 4] = pv;
                }
        }
    } else {
        float* op = (float*)outp;
#pragma unroll
        for (int mi = 0; mi < 4; ++mi)
#pragma unroll
            for (int ni = 0; ni < 4; ++ni)
#pragma unroll
                for (int r = 0; r < 4; ++r) {
                    int row = m0 + wm * 64 + mi * 16 + lq * 4 + r;
                    int col = n0 + wn * 32 + (ni & 1) * 16 + (ni >> 1) * 64 + l15;
                    op[(size_t)row * 2048 + col] = acc[mi][ni][r];
                }
    }
}

// ---------------- flash attention (causal), v5: balanced complementary pairs ----
// 512 blocks = 2 slots/CU. Dispatch fills slot 1 with blocks 0-255, slot 2 with
// 256-511; v4's t=15-(x>>5) paired (15,7),(14,6).. = 48..20 iters/CU (40%
// imbalance). v5: t = xq<8 ? 15-xq : xq-8 -> pairs (15,0),(14,1)..(8,7) = 34
// iters on EVERY CU. bh/XCD mapping unchanged (x&31).
__global__ __launch_bounds__(256, 2) void k_attn(const unsigned short* __restrict__ Qp,
                                                 const unsigned short* __restrict__ Kp,
                                                 const unsigned short* __restrict__ VTp,
                                                 unsigned short* __restrict__ ctx) {
    __shared__ __align__(16) unsigned short Ks[2][64 * 128];  // [kpos][d], granule-XOR swz
    __shared__ __align__(16) unsigned short Vs[2][128 * 64];  // [d][kpos], granule-XOR swz
    const int tid = threadIdx.x, w = tid >> 6, l = tid & 63;
    const int l31 = l & 31, hi = l >> 5;
    const int x = blockIdx.x, bh = x & 31;
    const int xq = x >> 5;
    const int t = (xq < 8) ? (15 - xq) : (xq - 8);  // complementary pairing
    const int b = bh >> 4, h = bh & 15;
    const size_t b2048 = (size_t)b * 2048;
    const int h128 = h * 128;
    const size_t bh128 = (size_t)bh * 128;

    auto stage = [&](int kv) {
        const int bsel = kv & 1;
        const size_t kvoff = (size_t)kv * 64;
#pragma unroll
        for (int i = 0; i < 4; ++i) {
            int gi = w * 256 + i * 64 + l;          // K: 64 rows x 16 granules
            int row = gi >> 4, g = gi & 15;
            int sg = g ^ (row & 7);
            const unsigned short* src = Kp + (b2048 + kvoff + row) * 2048 + h128 + sg * 8;
            __builtin_amdgcn_global_load_lds((const void*)src,
                                             (void*)&Ks[bsel][w * 2048 + i * 512], 16, 0, 0);
        }
#pragma unroll
        for (int i = 0; i < 4; ++i) {
            int gi = w * 256 + i * 64 + l;          // V: 128 rows x 8 granules
            int row = gi >> 3, g = gi & 7;
            int sg = g ^ (row & 7);
            const unsigned short* src = VTp + (bh128 + row) * 2048 + kvoff + sg * 8;
            __builtin_amdgcn_global_load_lds((const void*)src,
                                             (void*)&Vs[bsel][w * 2048 + i * 512], 16, 0, 0);
        }
    };

    const int q0 = t * 128;
    const int wrow0 = q0 + w * 32;
    const int qg = wrow0 + l31;          // this lane's q row

    // Q in registers: B-frag layout, q = l31, d = ds*16 + hi*8 + j
    bf16x8 qf[8];
    {
        const unsigned short* qb = Qp + (b2048 + qg) * 2048 + h128 + hi * 8;
#pragma unroll
        for (int ds = 0; ds < 8; ++ds) qf[ds] = *(const bf16x8*)(qb + ds * 16);
#pragma unroll
        for (int ds = 0; ds < 8; ++ds) asm volatile("" ::"v"(qf[ds]));
    }
    f32x16 Oa[4] = {};
    float m2 = -1e30f, l2 = 0.f;
    const int kvmax = 2 * t + 1;

    stage(0);
    for (int kv = 0; kv <= kvmax; ++kv) {
        const int cur = kv & 1;
        if (kv < kvmax) {
            stage(kv + 1);
            asm volatile("s_waitcnt vmcnt(8)" ::: "memory");
        } else {
            asm volatile("s_waitcnt vmcnt(0)" ::: "memory");
        }
        __builtin_amdgcn_s_barrier();
        __builtin_amdgcn_sched_barrier(0);

        const int kvb = kv * 64;
        if (kvb <= wrow0 + 31) {  // wave has unmasked rows
            // S[kpos][q] = K·Q^T : A = K rows, B = Q
            f32x16 S[2] = {};
            __builtin_amdgcn_s_setprio(1);
#pragma unroll
            for (int ds = 0; ds < 8; ++ds)
#pragma unroll
                for (int st = 0; st < 2; ++st) {
                    int row = st * 32 + l31;
                    int g = (ds * 2 + hi) ^ (row & 7);
                    bf16x8 kf = *(const bf16x8*)&Ks[cur][row * 128 + g * 8];
                    S[st] = __builtin_amdgcn_mfma_f32_32x32x16_bf16(kf, qf[ds], S[st], 0, 0, 0);
                }
            __builtin_amdgcn_s_setprio(0);

            if (kvb + 63 > wrow0) {  // diagonal: elementwise causal mask
#pragma unroll
                for (int st = 0; st < 2; ++st)
#pragma unroll
                    for (int r = 0; r < 16; ++r) {
                        int kpos = kvb + st * 32 + (r & 3) + 8 * (r >> 2) + 4 * hi;
                        if (kpos > qg) S[st][r] = -1e30f;
                    }
            }

            // in-lane softmax (lane owns one P-row; l^32 partner shares q)
            float pmax = -1e30f;
#pragma unroll
            for (int st = 0; st < 2; ++st)
#pragma unroll
                for (int r = 0; r < 16; ++r) pmax = fmaxf(pmax, S[st][r]);
            pmax = fmaxf(pmax, __shfl_xor(pmax, 32));
            if (__any(pmax > m2 + 8.0f)) {  // defer-max (T13)
                float mn = fmaxf(m2, pmax);
                float sc = __builtin_amdgcn_exp2f(m2 - mn);
                m2 = mn;
                l2 *= sc;
#pragma unroll
                for (int dt = 0; dt < 4; ++dt)
#pragma unroll
                    for (int e = 0; e < 16; ++e) Oa[dt][e] *= sc;
            }
            float rs = 0.f;
#pragma unroll
            for (int st = 0; st < 2; ++st)
#pragma unroll
                for (int r = 0; r < 16; ++r) {
                    float p = __builtin_amdgcn_exp2f(S[st][r] - m2);
                    S[st][r] = p;
                    rs += p;
                }
            rs += __shfl_xor(rs, 32);
            l2 += rs;

            // repack P -> B-frags via hw cvt_pk (k = hi*8+j per 16-kpos step)
            bf16x8 pfrag[4];
#pragma unroll
            for (int ks = 0; ks < 4; ++ks) {
                const int st = ks >> 1, base = (ks & 1) * 8;
                unsigned int x0 = cvtpk(S[st][base + 0], S[st][base + 1]);
                unsigned int x1 = cvtpk(S[st][base + 2], S[st][base + 3]);
                unsigned int y0 = cvtpk(S[st][base + 4], S[st][base + 5]);
                unsigned int y1 = cvtpk(S[st][base + 6], S[st][base + 7]);
                unsigned int t0 = hi ? x0 : y0, t1 = hi ? x1 : y1;
                t0 = (unsigned int)__shfl_xor((int)t0, 32);
                t1 = (unsigned int)__shfl_xor((int)t1, 32);
                u32x4 fw;
                fw.x = hi ? t0 : x0;
                fw.y = hi ? t1 : x1;
                fw.z = hi ? y0 : t0;
                fw.w = hi ? y1 : t1;
                pfrag[ks] = __builtin_bit_cast(bf16x8, fw);
            }

            // O[d][q] += Vt·P : A = Vt rows, B = P
            __builtin_amdgcn_s_setprio(1);
#pragma unroll
            for (int ks = 0; ks < 4; ++ks)
#pragma unroll
                for (int dt = 0; dt < 4; ++dt) {
                    int row = dt * 32 + l31;
                    int g = (ks * 2 + hi) ^ (row & 7);
                    bf16x8 vf = *(const bf16x8*)&Vs[cur][row * 64 + g * 8];
                    Oa[dt] = __builtin_amdgcn_mfma_f32_32x32x16_bf16(vf, pfrag[ks], Oa[dt], 0, 0, 0);
                }
            __builtin_amdgcn_s_setprio(0);
        }
        __builtin_amdgcn_sched_barrier(0);
        __builtin_amdgcn_s_barrier();
    }

    // epilogue: d = dt*32 + (r&3) + 8*(r>>2) + 4*hi -> 8B packed stores
    float inv = 1.0f / l2;
    unsigned short* cb = ctx + (b2048 + qg) * 2048 + h128;
#pragma unroll
    for (int dt = 0; dt < 4; ++dt)
#pragma unroll
        for (int g = 0; g < 4; ++g) {
            uint2 pv;
            pv.x = cvtpk(Oa[dt][4 * g + 0] * inv, Oa[dt][4 * g + 1] * inv);
            pv.y = cvtpk(Oa[dt][4 * g + 2] * inv, Oa[dt][4 * g + 3] * inv);
            *(uint2*)(cb + dt * 32 + 8 * g + 4 * hi) = pv;
        }
}

// ---------------- launch ----------------

extern "C" void kernel_launch(void* const* d_in, const int* in_sizes, int n_in,
                              void* d_out, int out_size, void* d_ws, size_t ws_size,
                              hipStream_t stream) {
    const float* x  = (const float*)d_in[0];
    const float* wq = (const float*)d_in[1];
    const float* wk = (const float*)d_in[2];
    const float* wv = (const float*)d_in[3];
    const float* wo = (const float*)d_in[4];

    char* ws = (char*)d_ws;
    unsigned short* xb  = (unsigned short*)(ws);                 // 16,777,216 B (reused as ctx)
    unsigned short* wT  = (unsigned short*)(ws + 16777216);      // 33,554,432 B [4][2048][2048]
    unsigned short* qkv = (unsigned short*)(ws + 50331648);      // 50,331,648 B [3][4096][2048] (V third unused)
    unsigned short* vT  = (unsigned short*)(ws + 100663296);     // 16,777,216 B [2][16][128][2048]
    unsigned short* ctx = xb;                                    // xb dead after gemm0

    k_conv_x<<<8192, 256, 0, stream>>>(x, xb, 2097152);
    k_wT<<<dim3(64, 64, 4), 256, 0, stream>>>(wq, wk, wv, wo, wT);
    gemm_bt<0><<<dim3(48, 32), 256, 0, stream>>>(xb, wT, (void*)qkv, vT, 4096, 6144, 2048);
    k_attn<<<512, 256, 0, stream>>>(qkv, qkv + 8388608, vT, ctx);
    gemm_bt<1><<<dim3(16, 32), 256, 0, stream>>>(ctx, wT + (size_t)3 * 4194304, d_out, vT,
                                                 4096, 2048, 2048);
}

// Round 18
// 240.082 us; speedup vs baseline: 1.0009x; 1.0007x over previous
//
#include <hip/hip_runtime.h>
#include <hip/hip_bf16.h>

typedef __attribute__((ext_vector_type(8))) short bf16x8;
typedef __attribute__((ext_vector_type(4))) float f32x4;
typedef __attribute__((ext_vector_type(16))) float f32x16;
typedef __attribute__((ext_vector_type(4))) unsigned int u32x4;

__device__ inline unsigned short f2bf(float f) {
    unsigned int u = __builtin_bit_cast(unsigned int, f);
    u += 0x7FFFu + ((u >> 16) & 1u);
    return (unsigned short)(u >> 16);
}
__device__ inline float bf2f(unsigned short h) {
    unsigned int u = ((unsigned int)h) << 16;
    return __builtin_bit_cast(float, u);
}
// hardware packed f32->bf16 (RNE), gfx950: no builtin -> inline asm
__device__ inline unsigned int cvtpk(float lo, float hi) {
    unsigned int r;
    asm("v_cvt_pk_bf16_f32 %0, %1, %2" : "=v"(r) : "v"(lo), "v"(hi));
    return r;
}

// ---------------- conversion kernels ----------------

__global__ void k_conv_x(const float* __restrict__ in, unsigned short* __restrict__ out, int n4) {
    int i = blockIdx.x * blockDim.x + threadIdx.x;
    if (i >= n4) return;
    float4 v = ((const float4*)in)[i];
    uint2 o;
    o.x = (unsigned)f2bf(v.x) | ((unsigned)f2bf(v.y) << 16);
    o.y = (unsigned)f2bf(v.z) | ((unsigned)f2bf(v.w) << 16);
    ((uint2*)out)[i] = o;
}

// W fp32 [2048][2048] -> W^T bf16 [2048][2048]; z selects weight
__global__ void k_wT(const float* __restrict__ w0, const float* __restrict__ w1,
                     const float* __restrict__ w2, const float* __restrict__ w3,
                     unsigned short* __restrict__ out) {
    __shared__ float tile[32][33];
    int z = blockIdx.z;
    const float* W = (z == 0) ? w0 : (z == 1) ? w1 : (z == 2) ? w2 : w3;
    unsigned short* O = out + (size_t)z * 2048 * 2048;
    int n0 = blockIdx.x * 32, k0 = blockIdx.y * 32;
    int tx = threadIdx.x & 31, ty = threadIdx.x >> 5;
#pragma unroll
    for (int j = 0; j < 4; ++j)
        tile[ty + j * 8][tx] = W[(size_t)(k0 + ty + j * 8) * 2048 + n0 + tx];
    __syncthreads();
#pragma unroll
    for (int j = 0; j < 4; ++j)
        O[(size_t)(n0 + ty + j * 8) * 2048 + k0 + tx] = f2bf(tile[tx][ty + j * 8]);
}

// ---------------- GEMM: C[M][N] = A[M][K] * Bt[N][K]^T ----------------
// R3 hot loop (128x128 tile, 4 waves, 2-barrier, gload_lds w16, granule-XOR).
// Wave N-columns remapped to wn*32 + (ni&1)*16 + (ni>>1)*64 so each lane holds
// RoPE pairs (d, d+64) in (ni, ni+2).
// Config A (empirical best): scattered fused epilogues, on-the-fly trig.
template <int OUT_MODE>
__global__ __launch_bounds__(256, 6) void gemm_bt(const unsigned short* __restrict__ A,
                                                  const unsigned short* __restrict__ Bt,
                                                  void* __restrict__ outp,
                                                  unsigned short* __restrict__ vtp,
                                                  int M, int N, int K) {
    __shared__ __align__(16) unsigned short As[128 * 64];
    __shared__ __align__(16) unsigned short Bs[128 * 64];
    const int tid = threadIdx.x, w = tid >> 6, l = tid & 63;
    const int m0 = blockIdx.y * 128, n0 = blockIdx.x * 128;
    const int wm = w >> 1, wn = w & 1;
    const int l15 = l & 15, lq = l >> 4;
    f32x4 acc[4][4] = {};
    const int lr = l >> 3, lg = l & 7;
    const int srcg = lg ^ lr;  // source granule (row&7 == lr since r0 % 8 == 0)

    const int nkt = K >> 6;
    for (int kt = 0; kt < nkt; ++kt) {
        if (kt) __syncthreads();
#pragma unroll
        for (int i = 0; i < 4; ++i) {
            int r0 = (w * 4 + i) * 8;
            int row = r0 + lr;
            const unsigned short* sa = A + (size_t)(m0 + row) * K + kt * 64 + srcg * 8;
            __builtin_amdgcn_global_load_lds((const void*)sa, (void*)&As[(w * 4 + i) * 512], 16, 0, 0);
            const unsigned short* sb = Bt + (size_t)(n0 + row) * K + kt * 64 + srcg * 8;
            __builtin_amdgcn_global_load_lds((const void*)sb, (void*)&Bs[(w * 4 + i) * 512], 16, 0, 0);
        }
        __syncthreads();
#pragma unroll
        for (int kb = 0; kb < 2; ++kb) {
            bf16x8 af[4], bfr[4];
#pragma unroll
            for (int mi = 0; mi < 4; ++mi) {
                int row = wm * 64 + mi * 16 + l15;
                int g = (kb * 4 + lq) ^ (row & 7);
                af[mi] = *(const bf16x8*)&As[row * 64 + g * 8];
            }
#pragma unroll
            for (int ni = 0; ni < 4; ++ni) {
                int row = wn * 32 + (ni & 1) * 16 + (ni >> 1) * 64 + l15;  // colmap
                int g = (kb * 4 + lq) ^ (row & 7);
                bfr[ni] = *(const bf16x8*)&Bs[row * 64 + g * 8];
            }
#pragma unroll
            for (int mi = 0; mi < 4; ++mi)
#pragma unroll
                for (int ni = 0; ni < 4; ++ni)
                    acc[mi][ni] = __builtin_amdgcn_mfma_f32_16x16x32_bf16(af[mi], bfr[ni],
                                                                          acc[mi][ni], 0, 0, 0);
        }
    }
    __builtin_amdgcn_sched_barrier(0);  // keep epilogue out of the K-loop

    if constexpr (OUT_MODE == 0) {
        const int tsel = n0 >> 11, nloc = n0 & 2047;
        if (tsel < 2) {
            // Q/K: RoPE in-register, trig on the fly (no memory traffic).
            unsigned short* op = (unsigned short*)outp + (size_t)tsel * M * 2048;
            const float scale = (tsel == 0) ? 0.12751742f : 1.0f;  // log2e/sqrt(128)
#pragma unroll
            for (int ni = 0; ni < 2; ++ni) {
                const int i = wn * 32 + ni * 16 + l15;  // d in [0,64)
                // rev_freq = 10000^(-i/64) / (2*pi)
                const float rf =
                    __builtin_amdgcn_exp2f(-(float)i * 0.20762051f - 2.6514961f);
#pragma unroll
                for (int mi = 0; mi < 4; ++mi)
#pragma unroll
                    for (int r = 0; r < 4; ++r) {
                        int row = m0 + wm * 64 + mi * 16 + lq * 4 + r;
                        int sp = row & 2047;
                        float rev = __builtin_amdgcn_fractf((float)sp * rf);
                        float cs = __builtin_amdgcn_cosf(rev);   // cos(2*pi*rev)
                        float sn = __builtin_amdgcn_sinf(rev);   // sin(2*pi*rev)
                        float a = acc[mi][ni][r], bb = acc[mi][ni + 2][r];
                        op[(size_t)row * 2048 + nloc + i]      = f2bf((a * cs - bb * sn) * scale);
                        op[(size_t)row * 2048 + nloc + i + 64] = f2bf((bb * cs + a * sn) * scale);
                    }
            }
        } else {
            // V: fused transpose -> vT[(b*16+h)*128 + d][s], packed 8B along s
            const int h = nloc >> 7;
            const int bsel = m0 >> 11;
            const int sp0 = (m0 & 2047) + wm * 64;
#pragma unroll
            for (int mi = 0; mi < 4; ++mi)
#pragma unroll
                for (int ni = 0; ni < 4; ++ni) {
                    int d = wn * 32 + (ni & 1) * 16 + (ni >> 1) * 64 + l15;
                    uint2 pv;
                    pv.x = cvtpk(acc[mi][ni][0], acc[mi][ni][1]);
                    pv.y = cvtpk(acc[mi][ni][2], acc[mi][ni][3]);
                    *(uint2*)&vtp[((size_t)((bsel * 16 + h) * 128 + d)) * 2048 + sp0 + mi * 16 + lq * 4] = pv;
                }
        }
    } else {
        float* op = (float*)outp;
#pragma unroll
        for (int mi = 0; mi < 4; ++mi)
#pragma unroll
            for (int ni = 0; ni < 4; ++ni)
#pragma unroll
                for (int r = 0; r < 4; ++r) {
                    int row = m0 + wm * 64 + mi * 16 + lq * 4 + r;
                    int col = n0 + wn * 32 + (ni & 1) * 16 + (ni >> 1) * 64 + l15;
                    op[(size_t)row * 2048 + col] = acc[mi][ni][r];
                }
    }
}

// ---------------- flash attention (causal), v6: pipelined iteration ----------
// [stage(kv+2) | softmax(kv) under load latency] -> vmcnt(8) -> bar ->
// [QK(kv+1) + PV(kv): merged 32-MFMA setprio cluster] -> bar -> S<-Sn.
// K double-buffered (QK(kv) retired a barrier before stage(kv+2) hits Ks[kv&1]);
// V 3-slot ring (stage(kv+2) slot == PV(kv-1) slot, retired behind end barrier).
// LDS 80KB -> 2 blocks/CU. All barriers unconditional.
__global__ __launch_bounds__(256, 2) void k_attn(const unsigned short* __restrict__ Qp,
                                                 const unsigned short* __restrict__ Kp,
                                                 const unsigned short* __restrict__ VTp,
                                                 unsigned short* __restrict__ ctx) {
    __shared__ __align__(16) unsigned short Ks[2][64 * 128];  // [kpos][d], granule-XOR swz
    __shared__ __align__(16) unsigned short Vs[3][128 * 64];  // [d][kpos], granule-XOR swz
    const int tid = threadIdx.x, w = tid >> 6, l = tid & 63;
    const int l31 = l & 31, hi = l >> 5;
    const int x = blockIdx.x, bh = x & 31;
    const int xq = x >> 5;
    const int t = (xq < 8) ? (15 - xq) : (xq - 8);
    const int b = bh >> 4, h = bh & 15;
    const size_t b2048 = (size_t)b * 2048;
    const int h128 = h * 128;
    const size_t bh128 = (size_t)bh * 128;

    auto stageK = [&](int kv) {
        const size_t kvoff = (size_t)kv * 64;
        unsigned short* kd = Ks[kv & 1];
#pragma unroll
        for (int i = 0; i < 4; ++i) {
            int gi = w * 256 + i * 64 + l;          // 64 rows x 16 granules
            int row = gi >> 4, g = gi & 15;
            int sg = g ^ (row & 7);
            const unsigned short* src = Kp + (b2048 + kvoff + row) * 2048 + h128 + sg * 8;
            __builtin_amdgcn_global_load_lds((const void*)src,
                                             (void*)&kd[w * 2048 + i * 512], 16, 0, 0);
        }
    };
    auto stageV = [&](int kv, int slot) {
        const size_t kvoff = (size_t)kv * 64;
        unsigned short* vd = Vs[slot];
#pragma unroll
        for (int i = 0; i < 4; ++i) {
            int gi = w * 256 + i * 64 + l;          // 128 rows x 8 granules
            int row = gi >> 3, g = gi & 7;
            int sg = g ^ (row & 7);
            const unsigned short* src = VTp + (bh128 + row) * 2048 + kvoff + sg * 8;
            __builtin_amdgcn_global_load_lds((const void*)src,
                                             (void*)&vd[w * 2048 + i * 512], 16, 0, 0);
        }
    };

    const int q0 = t * 128;
    const int wrow0 = q0 + w * 32;
    const int wlim = wrow0 + 31;
    const int qg = wrow0 + l31;          // this lane's q row

    // Q in registers: B-frag layout, q = l31, d = ds*16 + hi*8 + j
    bf16x8 qf[8];
    {
        const unsigned short* qb = Qp + (b2048 + qg) * 2048 + h128 + hi * 8;
#pragma unroll
        for (int ds = 0; ds < 8; ++ds) qf[ds] = *(const bf16x8*)(qb + ds * 16);
#pragma unroll
        for (int ds = 0; ds < 8; ++ds) asm volatile("" ::"v"(qf[ds]));
    }
    f32x16 Oa[4] = {};
    float m2 = -1e30f, l2 = 0.f;
    const int kvmax = 2 * t + 1;

    // prologue: stage kv0, kv1; compute QK(0)
    stageK(0); stageV(0, 0);
    stageK(1); stageV(1, 1);
    asm volatile("s_waitcnt vmcnt(8)" ::: "memory");  // kv0 landed (kv1 in flight)
    __builtin_amdgcn_s_barrier();
    __builtin_amdgcn_sched_barrier(0);

    f32x16 S[2] = {};
    {
#pragma unroll
        for (int ds = 0; ds < 8; ++ds)
#pragma unroll
            for (int st = 0; st < 2; ++st) {
                int row = st * 32 + l31;
                int g = (ds * 2 + hi) ^ (row & 7);
                bf16x8 kf = *(const bf16x8*)&Ks[0][row * 128 + g * 8];
                S[st] = __builtin_amdgcn_mfma_f32_32x32x16_bf16(kf, qf[ds], S[st], 0, 0, 0);
            }
        if (63 > wrow0) {  // kv=0 diagonal
#pragma unroll
            for (int st = 0; st < 2; ++st)
#pragma unroll
                for (int r = 0; r < 16; ++r) {
                    int kpos = st * 32 + (r & 3) + 8 * (r >> 2) + 4 * hi;
                    if (kpos > qg) S[st][r] = -1e30f;
                }
        }
    }
    __builtin_amdgcn_s_barrier();  // all waves past Ks[0]/Vs reads before loop stages

    int vp = 0;  // V ring slot of kv
    for (int kv = 0; kv <= kvmax; ++kv) {
        const bool act = (kv * 64 <= wlim);
        const bool haveNext = (kv < kvmax);
        if (kv + 2 <= kvmax) {
            int s2 = vp + 2; if (s2 >= 3) s2 -= 3;
            stageK(kv + 2);
            stageV(kv + 2, s2);
        }

        bf16x8 pfrag[4];
        if (act) {
            // in-lane softmax on S (overlaps stage latency)
            float pmax = -1e30f;
#pragma unroll
            for (int st = 0; st < 2; ++st)
#pragma unroll
                for (int r = 0; r < 16; ++r) pmax = fmaxf(pmax, S[st][r]);
            pmax = fmaxf(pmax, __shfl_xor(pmax, 32));
            if (__any(pmax > m2 + 8.0f)) {  // defer-max (T13)
                float mn = fmaxf(m2, pmax);
                float sc = __builtin_amdgcn_exp2f(m2 - mn);
                m2 = mn;
                l2 *= sc;
#pragma unroll
                for (int dt = 0; dt < 4; ++dt)
#pragma unroll
                    for (int e = 0; e < 16; ++e) Oa[dt][e] *= sc;
            }
            float rs = 0.f;
#pragma unroll
            for (int st = 0; st < 2; ++st)
#pragma unroll
                for (int r = 0; r < 16; ++r) {
                    float p = __builtin_amdgcn_exp2f(S[st][r] - m2);
                    S[st][r] = p;
                    rs += p;
                }
            rs += __shfl_xor(rs, 32);
            l2 += rs;

            // repack P -> B-frags via hw cvt_pk
#pragma unroll
            for (int ks = 0; ks < 4; ++ks) {
                const int st = ks >> 1, base = (ks & 1) * 8;
                unsigned int x0 = cvtpk(S[st][base + 0], S[st][base + 1]);
                unsigned int x1 = cvtpk(S[st][base + 2], S[st][base + 3]);
                unsigned int y0 = cvtpk(S[st][base + 4], S[st][base + 5]);
                unsigned int y1 = cvtpk(S[st][base + 6], S[st][base + 7]);
                unsigned int t0 = hi ? x0 : y0, t1 = hi ? x1 : y1;
                t0 = (unsigned int)__shfl_xor((int)t0, 32);
                t1 = (unsigned int)__shfl_xor((int)t1, 32);
                u32x4 fw;
                fw.x = hi ? t0 : x0;
                fw.y = hi ? t1 : x1;
                fw.z = hi ? y0 : t0;
                fw.w = hi ? y1 : t1;
                pfrag[ks] = __builtin_bit_cast(bf16x8, fw);
            }
        }

        if (kv + 2 <= kvmax) {
            asm volatile("s_waitcnt vmcnt(8)" ::: "memory");  // kv+1 landed, kv+2 in flight
        } else {
            asm volatile("s_waitcnt vmcnt(0)" ::: "memory");  // tail drain
        }
        __builtin_amdgcn_s_barrier();
        __builtin_amdgcn_sched_barrier(0);

        // merged MFMA cluster: QK(kv+1) + PV(kv)
        f32x16 Sn[2] = {};
        __builtin_amdgcn_s_setprio(1);
        if (haveNext && (kv + 1) * 64 <= wlim) {
            const unsigned short* kb = Ks[(kv + 1) & 1];
#pragma unroll
            for (int ds = 0; ds < 8; ++ds)
#pragma unroll
                for (int st = 0; st < 2; ++st) {
                    int row = st * 32 + l31;
                    int g = (ds * 2 + hi) ^ (row & 7);
                    bf16x8 kf = *(const bf16x8*)&kb[row * 128 + g * 8];
                    Sn[st] = __builtin_amdgcn_mfma_f32_32x32x16_bf16(kf, qf[ds], Sn[st], 0, 0, 0);
                }
        }
        if (act) {
            const unsigned short* vb = Vs[vp];
#pragma unroll
            for (int ks = 0; ks < 4; ++ks)
#pragma unroll
                for (int dt = 0; dt < 4; ++dt) {
                    int row = dt * 32 + l31;
                    int g = (ks * 2 + hi) ^ (row & 7);
                    bf16x8 vf = *(const bf16x8*)&vb[row * 64 + g * 8];
                    Oa[dt] = __builtin_amdgcn_mfma_f32_32x32x16_bf16(vf, pfrag[ks], Oa[dt], 0, 0, 0);
                }
        }
        __builtin_amdgcn_s_setprio(0);

        // diagonal mask for kv+1 (on Sn, outside MFMA cluster)
        if (haveNext && (kv + 1) * 64 <= wlim && (kv + 1) * 64 + 63 > wrow0) {
            const int kvb = (kv + 1) * 64;
#pragma unroll
            for (int st = 0; st < 2; ++st)
#pragma unroll
                for (int r = 0; r < 16; ++r) {
                    int kpos = kvb + st * 32 + (r & 3) + 8 * (r >> 2) + 4 * hi;
                    if (kpos > qg) Sn[st][r] = -1e30f;
                }
        }
        __builtin_amdgcn_sched_barrier(0);
        __builtin_amdgcn_s_barrier();
        S[0] = Sn[0];
        S[1] = Sn[1];
        ++vp; if (vp == 3) vp = 0;
    }

    // epilogue: d = dt*32 + (r&3) + 8*(r>>2) + 4*hi -> 8B packed stores
    float inv = 1.0f / l2;
    unsigned short* cb = ctx + (b2048 + qg) * 2048 + h128;
#pragma unroll
    for (int dt = 0; dt < 4; ++dt)
#pragma unroll
        for (int g = 0; g < 4; ++g) {
            uint2 pv;
            pv.x = cvtpk(Oa[dt][4 * g + 0] * inv, Oa[dt][4 * g + 1] * inv);
            pv.y = cvtpk(Oa[dt][4 * g + 2] * inv, Oa[dt][4 * g + 3] * inv);
            *(uint2*)(cb + dt * 32 + 8 * g + 4 * hi) = pv;
        }
}

// ---------------- launch ----------------

extern "C" void kernel_launch(void* const* d_in, const int* in_sizes, int n_in,
                              void* d_out, int out_size, void* d_ws, size_t ws_size,
                              hipStream_t stream) {
    const float* x  = (const float*)d_in[0];
    const float* wq = (const float*)d_in[1];
    const float* wk = (const float*)d_in[2];
    const float* wv = (const float*)d_in[3];
    const float* wo = (const float*)d_in[4];

    char* ws = (char*)d_ws;
    unsigned short* xb  = (unsigned short*)(ws);                 // 16,777,216 B (reused as ctx)
    unsigned short* wT  = (unsigned short*)(ws + 16777216);      // 33,554,432 B [4][2048][2048]
    unsigned short* qkv = (unsigned short*)(ws + 50331648);      // 50,331,648 B [3][4096][2048] (V third unused)
    unsigned short* vT  = (unsigned short*)(ws + 100663296);     // 16,777,216 B [2][16][128][2048]
    unsigned short* ctx = xb;                                    // xb dead after gemm0

    k_conv_x<<<8192, 256, 0, stream>>>(x, xb, 2097152);
    k_wT<<<dim3(64, 64, 4), 256, 0, stream>>>(wq, wk, wv, wo, wT);
    gemm_bt<0><<<dim3(48, 32), 256, 0, stream>>>(xb, wT, (void*)qkv, vT, 4096, 6144, 2048);
    k_attn<<<512, 256, 0, stream>>>(qkv, qkv + 8388608, vT, ctx);
    gemm_bt<1><<<dim3(16, 32), 256, 0, stream>>>(ctx, wT + (size_t)3 * 4194304, d_out, vT,
                                                 4096, 2048, 2048);
}